// Round 4
// baseline (1066.637 us; speedup 1.0000x reference)
//
#include <hip/hip_runtime.h>
#include <hip/hip_bf16.h>
#include <cstdint>

#define B_    16
#define IC_   512
#define OC_   512
#define RES_  64
#define WDIM_ 512
#define HW_   4096

#define XROWS 10
#define XCOLS 66
#define XsEL (XROWS * XCOLS * 32)   // 21120 bf16 = 42.24 KB per buffer

typedef __attribute__((ext_vector_type(8))) short short8;
typedef __attribute__((ext_vector_type(4))) float f32x4;

__device__ __forceinline__ unsigned int f2bf_bits(float f) {
    unsigned int x = __builtin_bit_cast(unsigned int, f);
    x += 0x7fffu + ((x >> 16) & 1u);   // RNE; inputs finite
    return x >> 16;
}

// ---------------- K0: styles = w @ (aw/sqrt(512))^T + ab ----------------
__global__ __launch_bounds__(256) void k_styles(const float* __restrict__ w,
        const float* __restrict__ aw, const float* __restrict__ ab,
        float* __restrict__ styles) {
    int bx = blockIdx.x;                     // 0..2047
    int b = bx >> 7;
    int wave = threadIdx.x >> 6, lane = threadIdx.x & 63;
    int ic = ((bx & 127) << 2) + wave;
    const float* wr = w + b * WDIM_;
    const float* awr = aw + ic * WDIM_;
    float s = 0.f;
    #pragma unroll
    for (int j = 0; j < 8; ++j) {
        int k = lane + (j << 6);
        s += wr[k] * awr[k];
    }
    #pragma unroll
    for (int off = 32; off > 0; off >>= 1) s += __shfl_down(s, off);
    if (lane == 0) styles[b * IC_ + ic] = s * 0.044194173824159216f + ab[ic];
}

// ---------------- K1: S2[oc,ic] = sum_k cw^2 ; wbf = bf16 pack ------------
// wbf layout: [t(9)][chunk(16)][oc(512)][ic32]   (plain, 4.72 MB)
__global__ __launch_bounds__(256) void k_wprep(const float* __restrict__ cw,
        float* __restrict__ S2, unsigned short* __restrict__ wbf) {
    int gid = blockIdx.x * 256 + threadIdx.x;   // 0..262143
    int oc = gid >> 9, ic = gid & 511;
    const float* p = cw + gid * 9;
    float v[9]; float ss = 0.f;
    #pragma unroll
    for (int t = 0; t < 9; ++t) { v[t] = p[t]; ss += v[t] * v[t]; }
    S2[gid] = ss;
    int chunk = ic >> 5;
    int base = (chunk * 512 + oc) * 32 + (ic & 31);
    #pragma unroll
    for (int t = 0; t < 9; ++t)
        wbf[t * (16 * 512 * 32) + base] = (unsigned short)f2bf_bits(v[t]);
}

// ---------------- K2: dcoefs[b,oc] = rsqrt(sum_ic styles^2 * S2 + 1e-8) -----
__global__ __launch_bounds__(256) void k_dcoef(const float* __restrict__ styles,
        const float* __restrict__ S2, float* __restrict__ dcoefs) {
    int bx = blockIdx.x;
    int b = bx >> 7;
    int wave = threadIdx.x >> 6, lane = threadIdx.x & 63;
    int oc = ((bx & 127) << 2) + wave;
    const float* st = styles + b * IC_;
    const float* s2 = S2 + oc * IC_;
    float s = 0.f;
    #pragma unroll
    for (int j = 0; j < 8; ++j) {
        int k = lane + (j << 6);
        float a = st[k];
        s += a * a * s2[k];
    }
    #pragma unroll
    for (int off = 32; off > 0; off >>= 1) s += __shfl_down(s, off);
    if (lane == 0) dcoefs[b * OC_ + oc] = rsqrtf(s + 1e-8f);
}

// ---------------- K3: main conv -------------------------------------------
// grid (8 nt, 4 oct, 16 b) = 512 blocks, 512 thr (8 waves), 1 block/CU.
// BM=128 oc (2 wave-tiles of 64), BN=512 (8 rows x 64 cols), wave tile 64x128.
// Double-buffered Xs + async-staged x (T14): issue loads early, write late,
// 1 barrier per c-chunk; 9 MFMA phases/chunk run barrier-free.
__global__ __launch_bounds__(512, 2) void k_conv(
        const float* __restrict__ x, const float* __restrict__ styles,
        const float* __restrict__ dcoefs, const unsigned short* __restrict__ wbf,
        const float* __restrict__ bias, const float* __restrict__ noise,
        const float* __restrict__ nstr, float* __restrict__ out) {

    __shared__ __align__(16) unsigned short Xs[2 * XsEL];    // 84.48 KB
    __shared__ float st_s[IC_];                              // 2 KB

    const int tid = threadIdx.x;
    const int lane = tid & 63;
    const int wave = tid >> 6;                 // 0..7
    const int lane15 = lane & 15, kg = lane >> 4;
    const int wm = wave >> 2, wn = wave & 3;   // 2 x 4 wave grid
    const int nt = blockIdx.x, oct = blockIdx.y, b = blockIdx.z;
    const int oc0 = oct * 128, r0 = nt * 8;
    const float* xb = x + (size_t)b * IC_ * HW_;

    // stage decode: col = lane (coalesced), ic-quad = wave (uniform rows)
    const int scol = tid & 63;
    const int sicq = tid >> 6;                 // 0..7 (== wave)
    const int scl = scol + 1;
    const int sgp = (sicq >> 1) ^ ((scl >> 1) & 3);
    const int sel_base = scl * 32 + sgp * 8 + ((sicq & 1) << 2);

    // A (weights) from global, L1-cached; per-lane fixed offset
    const unsigned short* wlane =
        wbf + (size_t)(oc0 + wm * 64 + lane15) * 32 + (kg << 3);

    auto loadA = [&](int c2, int t2, short8* dst) {
        const unsigned short* g = wlane + (size_t)(t2 * 16 + c2) * (512 * 32);
        #pragma unroll
        for (int mf = 0; mf < 4; ++mf)
            dst[mf] = *(const short8*)(g + (mf << 9));
    };

    float v[5][4];   // 20 floats held across the T14 window

    auto stage_load = [&](int H, int c) {
        int icb = (c << 5) + (sicq << 2);
        #pragma unroll
        for (int s5 = 0; s5 < 5; ++s5) {
            int rl = H * 5 + s5;
            int grow = r0 - 1 + rl;
            if (grow >= 0 && grow < RES_) {
                const float* xr = xb + (size_t)icb * HW_ + grow * RES_ + scol;
                #pragma unroll
                for (int i = 0; i < 4; ++i)
                    v[s5][i] = xr[(size_t)i * HW_];
            }
        }
    };

    auto stage_store = [&](int H, int c, int buf) {
        int icb = (c << 5) + (sicq << 2);
        float sc[4];
        #pragma unroll
        for (int i = 0; i < 4; ++i) sc[i] = st_s[icb + i];
        unsigned short* Xb = Xs + buf * XsEL;
        #pragma unroll
        for (int s5 = 0; s5 < 5; ++s5) {
            int rl = H * 5 + s5;
            int grow = r0 - 1 + rl;
            if (grow >= 0 && grow < RES_) {
                unsigned int lo = f2bf_bits(v[s5][0] * sc[0]) |
                                  (f2bf_bits(v[s5][1] * sc[1]) << 16);
                unsigned int hi = f2bf_bits(v[s5][2] * sc[2]) |
                                  (f2bf_bits(v[s5][3] * sc[3]) << 16);
                *(uint2*)(&Xb[rl * (XCOLS * 32) + sel_base]) = make_uint2(lo, hi);
            }
        }
    };

    // prologue: zero both buffers (halo stays 0 forever), load styles
    {
        unsigned int* xz = (unsigned int*)Xs;
        for (int i = tid; i < XsEL; i += 512) xz[i] = 0u;   // XsEL dwords = 2*XsEL shorts
        for (int i = tid; i < IC_; i += 512) st_s[i] = styles[b * IC_ + i];
    }
    __syncthreads();
    stage_load(0, 0); stage_store(0, 0, 0);
    stage_load(1, 0); stage_store(1, 0, 0);
    __syncthreads();

    f32x4 acc[4][8];
    #pragma unroll
    for (int mf = 0; mf < 4; ++mf)
        #pragma unroll
        for (int nf = 0; nf < 8; ++nf)
            acc[mf][nf] = (f32x4){0.f, 0.f, 0.f, 0.f};

    short8 afc[4];
    loadA(0, 0, afc);

    for (int c = 0; c < 16; ++c) {
        const unsigned short* Xb = Xs + (c & 1) * XsEL;
        const bool st = (c < 15);
        if (st) stage_load(0, c + 1);           // issue early: latency hides under t=0..3
        #pragma unroll
        for (int t = 0; t < 9; ++t) {
            if (t == 4 && st) {                 // mid-chunk: commit half 0, issue half 1
                stage_store(0, c + 1, (c + 1) & 1);
                stage_load(1, c + 1);
            }
            short8 afn[4];
            {
                int c2 = (t < 8) ? c : ((c + 1) & 15);
                int t2 = (t < 8) ? (t + 1) : 0;
                loadA(c2, t2, afn);
            }
            const int kh = t / 3, kw = t % 3;
            short8 bfr[8];
            #pragma unroll
            for (int nf = 0; nf < 8; ++nf) {
                int rl = (wn << 1) + (nf >> 2) + kh;
                int cl = ((nf & 3) << 4) + lane15 + kw;
                int gp = kg ^ ((cl >> 1) & 3);
                int el = (rl * XCOLS + cl) * 32 + (gp << 3);
                bfr[nf] = *(const short8*)(Xb + el);
            }
            #pragma unroll
            for (int mf = 0; mf < 4; ++mf)
                #pragma unroll
                for (int nf = 0; nf < 8; ++nf)
                    acc[mf][nf] = __builtin_amdgcn_mfma_f32_16x16x32_bf16(
                        afc[mf], bfr[nf], acc[mf][nf], 0, 0, 0);
            #pragma unroll
            for (int mf = 0; mf < 4; ++mf) afc[mf] = afn[mf];
        }
        if (st) stage_store(1, c + 1, (c + 1) & 1);   // commit half 1
        __syncthreads();                               // buffer handoff
    }

    // epilogue: demod, noise, bias, lrelu*sqrt(2)
    const float nstrength = nstr[0];
    float* outb = out + (size_t)(b * OC_ + oc0) * HW_ + nt * (8 * RES_);
    float nz[8];
    #pragma unroll
    for (int nf = 0; nf < 8; ++nf) {
        int n = (wn << 7) + (nf << 4) + lane15;
        nz[nf] = noise[nt * 512 + n] * nstrength;
    }
    #pragma unroll
    for (int mf = 0; mf < 4; ++mf) {
        #pragma unroll
        for (int r = 0; r < 4; ++r) {
            int ocl = wm * 64 + (mf << 4) + (kg << 2) + r;
            float dc = dcoefs[b * OC_ + oc0 + ocl];
            float bv = bias[oc0 + ocl];
            #pragma unroll
            for (int nf = 0; nf < 8; ++nf) {
                int n = (wn << 7) + (nf << 4) + lane15;
                float vv = acc[mf][nf][r] * dc + nz[nf] + bv;
                vv = (vv >= 0.f ? vv : 0.2f * vv) * 1.4142135623730951f;
                outb[(size_t)ocl * HW_ + n] = vv;
            }
        }
    }
}

// ---------------- launch ---------------------------------------------------
extern "C" void kernel_launch(void* const* d_in, const int* in_sizes, int n_in,
                              void* d_out, int out_size, void* d_ws, size_t ws_size,
                              hipStream_t stream) {
    const float* x     = (const float*)d_in[0];
    const float* w     = (const float*)d_in[1];
    const float* cw    = (const float*)d_in[2];
    const float* aw    = (const float*)d_in[3];
    const float* ab    = (const float*)d_in[4];
    const float* bias  = (const float*)d_in[5];
    const float* noise = (const float*)d_in[6];
    const float* nstr  = (const float*)d_in[7];
    float* out = (float*)d_out;

    uint8_t* ws = (uint8_t*)d_ws;
    float* styles = (float*)ws;                              // 32 KB
    float* dcoefs = (float*)(ws + 32768);                    // 32 KB
    float* S2     = (float*)(ws + 65536);                    // 1 MB
    unsigned short* wbf = (unsigned short*)(ws + 65536 + 1048576);  // 4.72 MB

    hipLaunchKernelGGL(k_styles, dim3(2048), dim3(256), 0, stream, w, aw, ab, styles);
    hipLaunchKernelGGL(k_wprep,  dim3(1024), dim3(256), 0, stream, cw, S2, wbf);
    hipLaunchKernelGGL(k_dcoef,  dim3(2048), dim3(256), 0, stream, styles, S2, dcoefs);
    hipLaunchKernelGGL(k_conv, dim3(8, 4, 16), dim3(512), 0, stream,
                       x, styles, dcoefs, wbf, bias, noise, nstr, out);
}

// Round 7
// 756.468 us; speedup vs baseline: 1.4100x; 1.4100x over previous
//
#include <hip/hip_runtime.h>
#include <hip/hip_bf16.h>
#include <cstdint>

#define B_    16
#define IC_   512
#define OC_   512
#define RES_  64
#define WDIM_ 512
#define HW_   4096

#define XROWS 10
#define XCOLS 66
#define XsEL (XROWS * XCOLS * 32)   // 21120 shorts = 42240 B per buffer

typedef __attribute__((ext_vector_type(8))) short short8;
typedef __attribute__((ext_vector_type(4))) float f32x4;
typedef __attribute__((address_space(3))) unsigned int lds_uint;
typedef const __attribute__((address_space(1))) unsigned int g_uint;

__device__ __forceinline__ unsigned int f2bf_bits(float f) {
    unsigned int x = __builtin_bit_cast(unsigned int, f);
    x += 0x7fffu + ((x >> 16) & 1u);   // RNE; inputs finite
    return x >> 16;
}

// ---------------- K0: styles = w @ (aw/sqrt(512))^T + ab ----------------
__global__ __launch_bounds__(256) void k_styles(const float* __restrict__ w,
        const float* __restrict__ aw, const float* __restrict__ ab,
        float* __restrict__ styles) {
    int bx = blockIdx.x;                     // 0..2047
    int b = bx >> 7;
    int wave = threadIdx.x >> 6, lane = threadIdx.x & 63;
    int ic = ((bx & 127) << 2) + wave;
    const float* wr = w + b * WDIM_;
    const float* awr = aw + ic * WDIM_;
    float s = 0.f;
    #pragma unroll
    for (int j = 0; j < 8; ++j) {
        int k = lane + (j << 6);
        s += wr[k] * awr[k];
    }
    #pragma unroll
    for (int off = 32; off > 0; off >>= 1) s += __shfl_down(s, off);
    if (lane == 0) styles[b * IC_ + ic] = s * 0.044194173824159216f + ab[ic];
}

// ---------------- K1: S2[oc,ic] = sum_k cw^2 ; wbf = bf16 pack ------------
// wbf layout: [t(9)][chunk(16)][oc(512)][ic32]   (plain, 4.72 MB)
__global__ __launch_bounds__(256) void k_wprep(const float* __restrict__ cw,
        float* __restrict__ S2, unsigned short* __restrict__ wbf) {
    int gid = blockIdx.x * 256 + threadIdx.x;   // 0..262143
    int oc = gid >> 9, ic = gid & 511;
    const float* p = cw + gid * 9;
    float v[9]; float ss = 0.f;
    #pragma unroll
    for (int t = 0; t < 9; ++t) { v[t] = p[t]; ss += v[t] * v[t]; }
    S2[gid] = ss;
    int chunk = ic >> 5;
    int base = (chunk * 512 + oc) * 32 + (ic & 31);
    #pragma unroll
    for (int t = 0; t < 9; ++t)
        wbf[t * (16 * 512 * 32) + base] = (unsigned short)f2bf_bits(v[t]);
}

// ---------------- K1b: xpack = bf16(x * styles), swizzle baked -------------
// layout: [b(16)][c(16)][row(64)][col(64)][slot(32)] shorts (67.1 MB)
// slot s at column col: ic = c*32 + 8*((s>>3) ^ swz(col+1)) + (s&7),
// swz(cl) = (cl>>1)&3  -- matches k_conv's B-frag reader.
// Each thread writes one 16B unit -> exactly 2^22 threads = 16384 blocks.
__global__ __launch_bounds__(256) void k_xprep(const float* __restrict__ x,
        const float* __restrict__ styles, unsigned short* __restrict__ xpack) {
    unsigned int flat = blockIdx.x * 256 + threadIdx.x;   // 0..2^22-1
    int gp  = flat & 3;
    int col = (flat >> 2) & 63;
    int row = (flat >> 8) & 63;
    int c   = (flat >> 14) & 15;
    int b   = flat >> 18;                                  // 0..15
    int swz = ((col + 1) >> 1) & 3;
    int ic0 = c * 32 + 8 * (gp ^ swz);
    const float* xp = x + (size_t)(b * IC_ + ic0) * HW_ + row * RES_ + col;
    const float* st = styles + b * IC_ + ic0;
    unsigned int o[4];
    #pragma unroll
    for (int h = 0; h < 4; ++h) {
        float a0 = xp[(size_t)(2 * h) * HW_]     * st[2 * h];
        float a1 = xp[(size_t)(2 * h + 1) * HW_] * st[2 * h + 1];
        o[h] = f2bf_bits(a0) | (f2bf_bits(a1) << 16);
    }
    uint4* dst = (uint4*)(xpack + (size_t)flat * 8);
    *dst = make_uint4(o[0], o[1], o[2], o[3]);
}

// ---------------- K2: dcoefs[b,oc] = rsqrt(sum_ic styles^2 * S2 + 1e-8) -----
__global__ __launch_bounds__(256) void k_dcoef(const float* __restrict__ styles,
        const float* __restrict__ S2, float* __restrict__ dcoefs) {
    int bx = blockIdx.x;
    int b = bx >> 7;
    int wave = threadIdx.x >> 6, lane = threadIdx.x & 63;
    int oc = ((bx & 127) << 2) + wave;
    const float* st = styles + b * IC_;
    const float* s2 = S2 + oc * IC_;
    float s = 0.f;
    #pragma unroll
    for (int j = 0; j < 8; ++j) {
        int k = lane + (j << 6);
        float a = st[k];
        s += a * a * s2[k];
    }
    #pragma unroll
    for (int off = 32; off > 0; off >>= 1) s += __shfl_down(s, off);
    if (lane == 0) dcoefs[b * OC_ + oc] = rsqrtf(s + 1e-8f);
}

// ---------------- K3: main conv -------------------------------------------
// grid (8 nt, 4 oct, 16 b) = 512 blocks, 512 thr (8 waves), 1 block/CU.
// BM=128 oc, BN=512 (8 rows x 64 cols), wave tile 64x128.
// X staged by global_load_lds DMA from xpack (zero VALU staging), double-
// buffered; DMA count is compile-time (invalid halo rows -> dummy LDS row)
// so the waitcnt pass emits precise counted vmcnt; DMA issued at t==2 so
// phases 0-3 never wait on it. A from global (L1-resident).
__global__ __launch_bounds__(512, 2) void k_conv(
        const unsigned short* __restrict__ xpack,
        const float* __restrict__ dcoefs, const unsigned short* __restrict__ wbf,
        const float* __restrict__ bias, const float* __restrict__ noise,
        const float* __restrict__ nstr, float* __restrict__ out) {

    __shared__ __align__(16) unsigned short Xs[2 * XsEL + 2048];  // + dummy row

    const int tid = threadIdx.x;
    const int lane = tid & 63;
    const int wave = tid >> 6;                 // 0..7
    const int lane15 = lane & 15, kg = lane >> 4;
    const int wm = wave >> 2, wn = wave & 3;   // 2 x 4 wave grid
    const int nt = blockIdx.x, oct = blockIdx.y, b = blockIdx.z;
    const int oc0 = oct * 128, r0 = nt * 8;

    const unsigned short* xpk = xpack + (size_t)b * (16 * 64 * 2048);

    // DMA one chunk image (10 rows x 64 interior cols x 32 slots) into buf.
    // Thread tid -> row parity (tid>>8), 16B unit (tid&255) in a 4096B row.
    // Exactly 5 loads per thread ALWAYS (edge rows redirected to dummy).
    const int dhalf = tid >> 8;
    const int doff  = tid & 255;
    auto dma_chunk = [&](int c, int buf) {
        unsigned short* XbW = Xs + buf * XsEL;
        #pragma unroll
        for (int r = 0; r < 5; ++r) {
            int rl = r * 2 + dhalf;
            int grow = r0 - 1 + rl;                       // wave-uniform
            bool ok = (grow >= 0) && (grow < RES_);
            int gsrc = ok ? grow : (grow < 0 ? 0 : RES_ - 1);
            const unsigned short* src =
                xpk + ((size_t)((c << 6) + gsrc) << 11) + (doff << 3);
            unsigned short* ldst = ok
                ? (XbW + ((rl * XCOLS + 1) << 5) + (doff << 3))
                : (Xs + 2 * XsEL + (doff << 3));          // dummy row
            __builtin_amdgcn_global_load_lds((g_uint*)src, (lds_uint*)ldst,
                                             16, 0, 0);
        }
    };

    // A (weights) from global, L1-cached; per-lane fixed offset
    const unsigned short* wlane =
        wbf + (size_t)(oc0 + wm * 64 + lane15) * 32 + (kg << 3);
    auto loadA = [&](int c2, int t2, short8* dst) {
        const unsigned short* g = wlane + (size_t)(t2 * 16 + c2) * (512 * 32);
        #pragma unroll
        for (int mf = 0; mf < 4; ++mf)
            dst[mf] = *(const short8*)(g + (mf << 9));
    };

    // prologue: zero both buffers + dummy (halo stays 0 forever; DMA only
    // writes interior cl 1..64 of valid rows, or the dummy row)
    {
        unsigned int* xz = (unsigned int*)Xs;
        for (int i = tid; i < XsEL + 1024; i += 512) xz[i] = 0u;
    }
    __syncthreads();
    dma_chunk(0, 0);
    __syncthreads();                 // drains DMA (vmcnt 0) + barrier

    f32x4 acc[4][8];
    #pragma unroll
    for (int mf = 0; mf < 4; ++mf)
        #pragma unroll
        for (int nf = 0; nf < 8; ++nf)
            acc[mf][nf] = (f32x4){0.f, 0.f, 0.f, 0.f};

    for (int c = 0; c < 16; ++c) {
        const unsigned short* Xb = Xs + (c & 1) * XsEL;
        short8 afc[4];
        loadA(c, 0, afc);
        #pragma unroll
        for (int t = 0; t < 9; ++t) {
            short8 afn[4];
            if (t < 8) loadA(c, t + 1, afn);
            if (t == 2 && c < 15) dma_chunk(c + 1, (c + 1) & 1);
            const int kh = t / 3, kw = t % 3;
            short8 bfr[8];
            #pragma unroll
            for (int nf = 0; nf < 8; ++nf) {
                int rl = (wn << 1) + (nf >> 2) + kh;
                int cl = ((nf & 3) << 4) + lane15 + kw;
                int gp = kg ^ ((cl >> 1) & 3);
                int el = (rl * XCOLS + cl) * 32 + (gp << 3);
                bfr[nf] = *(const short8*)(Xb + el);
            }
            #pragma unroll
            for (int mf = 0; mf < 4; ++mf)
                #pragma unroll
                for (int nf = 0; nf < 8; ++nf)
                    acc[mf][nf] = __builtin_amdgcn_mfma_f32_16x16x32_bf16(
                        afc[mf], bfr[nf], acc[mf][nf], 0, 0, 0);
            if (t < 8) {
                #pragma unroll
                for (int mf = 0; mf < 4; ++mf) afc[mf] = afn[mf];
            }
        }
        __syncthreads();             // buffer handoff (drains DMA + LDS)
    }

    // epilogue: demod, noise, bias, lrelu*sqrt(2)
    const float nstrength = nstr[0];
    float* outb = out + (size_t)(b * OC_ + oc0) * HW_ + nt * (8 * RES_);
    float nz[8];
    #pragma unroll
    for (int nf = 0; nf < 8; ++nf) {
        int n = (wn << 7) + (nf << 4) + lane15;
        nz[nf] = noise[nt * 512 + n] * nstrength;
    }
    #pragma unroll
    for (int mf = 0; mf < 4; ++mf) {
        #pragma unroll
        for (int r = 0; r < 4; ++r) {
            int ocl = wm * 64 + (mf << 4) + (kg << 2) + r;
            float dc = dcoefs[b * OC_ + oc0 + ocl];
            float bv = bias[oc0 + ocl];
            #pragma unroll
            for (int nf = 0; nf < 8; ++nf) {
                int n = (wn << 7) + (nf << 4) + lane15;
                float vv = acc[mf][nf][r] * dc + nz[nf] + bv;
                vv = (vv >= 0.f ? vv : 0.2f * vv) * 1.4142135623730951f;
                outb[(size_t)ocl * HW_ + n] = vv;
            }
        }
    }
}

// ---------------- launch ---------------------------------------------------
extern "C" void kernel_launch(void* const* d_in, const int* in_sizes, int n_in,
                              void* d_out, int out_size, void* d_ws, size_t ws_size,
                              hipStream_t stream) {
    const float* x     = (const float*)d_in[0];
    const float* w     = (const float*)d_in[1];
    const float* cw    = (const float*)d_in[2];
    const float* aw    = (const float*)d_in[3];
    const float* ab    = (const float*)d_in[4];
    const float* bias  = (const float*)d_in[5];
    const float* noise = (const float*)d_in[6];
    const float* nstr  = (const float*)d_in[7];
    float* out = (float*)d_out;

    uint8_t* ws = (uint8_t*)d_ws;
    float* styles = (float*)ws;                              // 32 KB
    float* dcoefs = (float*)(ws + 32768);                    // 32 KB
    float* S2     = (float*)(ws + 65536);                    // 1 MB
    unsigned short* wbf   = (unsigned short*)(ws + 65536 + 1048576);  // 4.72 MB
    unsigned short* xpack = (unsigned short*)(ws + 8388608);          // 67.1 MB

    hipLaunchKernelGGL(k_styles, dim3(2048), dim3(256), 0, stream, w, aw, ab, styles);
    hipLaunchKernelGGL(k_xprep,  dim3(16384), dim3(256), 0, stream, x, styles, xpack);
    hipLaunchKernelGGL(k_wprep,  dim3(1024), dim3(256), 0, stream, cw, S2, wbf);
    hipLaunchKernelGGL(k_dcoef,  dim3(2048), dim3(256), 0, stream, styles, S2, dcoefs);
    hipLaunchKernelGGL(k_conv, dim3(8, 4, 16), dim3(512), 0, stream,
                       xpack, dcoefs, wbf, bias, noise, nstr, out);
}

// Round 9
// 662.590 us; speedup vs baseline: 1.6098x; 1.1417x over previous
//
#include <hip/hip_runtime.h>
#include <hip/hip_bf16.h>
#include <cstdint>

#define B_    16
#define IC_   512
#define OC_   512
#define RES_  64
#define WDIM_ 512
#define HW_   4096

#define XR6   6
#define XCOLS 66
#define XsEL6 (XR6 * XCOLS * 32)   // 12672 shorts = 25344 B per buffer

typedef __attribute__((ext_vector_type(8))) short short8;
typedef __attribute__((ext_vector_type(4))) float f32x4;
typedef __attribute__((address_space(3))) unsigned int lds_uint;
typedef const __attribute__((address_space(1))) unsigned int g_uint;

__device__ __forceinline__ unsigned int f2bf_bits(float f) {
    unsigned int x = __builtin_bit_cast(unsigned int, f);
    x += 0x7fffu + ((x >> 16) & 1u);   // RNE; inputs finite
    return x >> 16;
}

// ---------------- K0: styles = w @ (aw/sqrt(512))^T + ab ----------------
__global__ __launch_bounds__(256) void k_styles(const float* __restrict__ w,
        const float* __restrict__ aw, const float* __restrict__ ab,
        float* __restrict__ styles) {
    int bx = blockIdx.x;                     // 0..2047
    int b = bx >> 7;
    int wave = threadIdx.x >> 6, lane = threadIdx.x & 63;
    int ic = ((bx & 127) << 2) + wave;
    const float* wr = w + b * WDIM_;
    const float* awr = aw + ic * WDIM_;
    float s = 0.f;
    #pragma unroll
    for (int j = 0; j < 8; ++j) {
        int k = lane + (j << 6);
        s += wr[k] * awr[k];
    }
    #pragma unroll
    for (int off = 32; off > 0; off >>= 1) s += __shfl_down(s, off);
    if (lane == 0) styles[b * IC_ + ic] = s * 0.044194173824159216f + ab[ic];
}

// ---------------- K1: S2[oc,ic] = sum_k cw^2 ; wbf = bf16 pack ------------
// wbf layout: [t(9)][chunk(16)][oc(512)][ic32]   (plain, 4.72 MB)
__global__ __launch_bounds__(256) void k_wprep(const float* __restrict__ cw,
        float* __restrict__ S2, unsigned short* __restrict__ wbf) {
    int gid = blockIdx.x * 256 + threadIdx.x;   // 0..262143
    int oc = gid >> 9, ic = gid & 511;
    const float* p = cw + gid * 9;
    float v[9]; float ss = 0.f;
    #pragma unroll
    for (int t = 0; t < 9; ++t) { v[t] = p[t]; ss += v[t] * v[t]; }
    S2[gid] = ss;
    int chunk = ic >> 5;
    int base = (chunk * 512 + oc) * 32 + (ic & 31);
    #pragma unroll
    for (int t = 0; t < 9; ++t)
        wbf[t * (16 * 512 * 32) + base] = (unsigned short)f2bf_bits(v[t]);
}

// ---------------- K1b: xpack = bf16(x * styles), swizzle baked -------------
// layout: [b(16)][c(16)][row(64)][col(64)][slot(32)] shorts (67.1 MB)
// slot s at column col: ic = c*32 + 8*((s>>3) ^ swz(col+1)) + (s&7),
// swz(cl) = (cl>>1)&3  -- matches k_conv's B-frag reader.
// Each thread writes one 16B unit -> exactly 2^22 threads = 16384 blocks.
__global__ __launch_bounds__(256) void k_xprep(const float* __restrict__ x,
        const float* __restrict__ styles, unsigned short* __restrict__ xpack) {
    unsigned int flat = blockIdx.x * 256 + threadIdx.x;   // 0..2^22-1
    int gp  = flat & 3;
    int col = (flat >> 2) & 63;
    int row = (flat >> 8) & 63;
    int c   = (flat >> 14) & 15;
    int b   = flat >> 18;                                  // 0..15
    int swz = ((col + 1) >> 1) & 3;
    int ic0 = c * 32 + 8 * (gp ^ swz);
    const float* xp = x + (size_t)(b * IC_ + ic0) * HW_ + row * RES_ + col;
    const float* st = styles + b * IC_ + ic0;
    unsigned int o[4];
    #pragma unroll
    for (int h = 0; h < 4; ++h) {
        float a0 = xp[(size_t)(2 * h) * HW_]     * st[2 * h];
        float a1 = xp[(size_t)(2 * h + 1) * HW_] * st[2 * h + 1];
        o[h] = f2bf_bits(a0) | (f2bf_bits(a1) << 16);
    }
    uint4* dst = (uint4*)(xpack + (size_t)flat * 8);
    *dst = make_uint4(o[0], o[1], o[2], o[3]);
}

// ---------------- K2: dcoefs[b,oc] = rsqrt(sum_ic styles^2 * S2 + 1e-8) -----
__global__ __launch_bounds__(256) void k_dcoef(const float* __restrict__ styles,
        const float* __restrict__ S2, float* __restrict__ dcoefs) {
    int bx = blockIdx.x;
    int b = bx >> 7;
    int wave = threadIdx.x >> 6, lane = threadIdx.x & 63;
    int oc = ((bx & 127) << 2) + wave;
    const float* st = styles + b * IC_;
    const float* s2 = S2 + oc * IC_;
    float s = 0.f;
    #pragma unroll
    for (int j = 0; j < 8; ++j) {
        int k = lane + (j << 6);
        float a = st[k];
        s += a * a * s2[k];
    }
    #pragma unroll
    for (int off = 32; off > 0; off >>= 1) s += __shfl_down(s, off);
    if (lane == 0) dcoefs[b * OC_ + oc] = rsqrtf(s + 1e-8f);
}

// ---------------- K3: main conv -------------------------------------------
// 2048 blocks x 256 thr (4 waves), 3 blocks/CU (12 waves/CU).
// Block tile: 64 oc x 256 px (4 image rows); wave tile 64 oc x 64 px (1 row).
// bid decode keeps all 8 oct-blocks of one (b,nt) on the same XCD (bid%8
// invariant over oct) -> xpack chunk L2-resident, ~1x HBM fetch.
// X via global_load_lds DMA (6/thread, compile-time count; halo rows ->
// 1KB dummy with wave-uniform base), double-buffered, 1 barrier/chunk.
__global__ __launch_bounds__(256, 3) void k_conv(
        const unsigned short* __restrict__ xpack,
        const float* __restrict__ dcoefs, const unsigned short* __restrict__ wbf,
        const float* __restrict__ bias, const float* __restrict__ noise,
        const float* __restrict__ nstr, float* __restrict__ out) {

    __shared__ __align__(16) unsigned short Xs[2 * XsEL6 + 512];  // 51.7 KB

    const int tid = threadIdx.x;
    const int lane = tid & 63;
    const int wn = tid >> 6;                   // wave 0..3 = px-row owner
    const int lane15 = lane & 15, kg = lane >> 4;
    const int bid = blockIdx.x;
    const int oct = bid >> 8;                  // 0..7
    const int kk  = bid & 255;
    const int nt  = kk & 15;                   // 0..15 (4-row strip)
    const int b   = kk >> 4;                   // 0..15
    const int oc0 = oct * 64, r0 = nt * 4;

    const unsigned short* xpk = xpack + (size_t)b * (16 * 64 * 2048);

    // DMA one chunk image (6 rows x 64 cols x 32 slots = 24.75 KB) into buf.
    // Thread tid -> 16B unit tid within each 4096B row; 6 rows each.
    auto dma_chunk = [&](int c, int buf) {
        unsigned short* XbW = Xs + buf * XsEL6;
        #pragma unroll
        for (int r = 0; r < 6; ++r) {
            int grow = r0 - 1 + r;                        // wave-uniform
            bool ok = (grow >= 0) && (grow < RES_);
            int gsrc = ok ? grow : 0;
            const unsigned short* src =
                xpk + ((size_t)((c << 6) + gsrc) << 11) + (tid << 3);
            unsigned short* ldst = ok
                ? (XbW + ((r * XCOLS + 1) << 5) + (tid << 3))
                : (Xs + 2 * XsEL6 + (lane << 3));         // shared 1KB dummy
            __builtin_amdgcn_global_load_lds((g_uint*)src, (lds_uint*)ldst,
                                             16, 0, 0);
        }
    };

    // A (weights) from global, L1/L2-cached; all 4 waves share the same frags
    const unsigned short* wlane = wbf + (size_t)(oc0 + lane15) * 32 + (kg << 3);
    auto loadA = [&](int c2, int t2, short8* dst) {
        const unsigned short* g = wlane + (size_t)(t2 * 16 + c2) * (512 * 32);
        #pragma unroll
        for (int mf = 0; mf < 4; ++mf)
            dst[mf] = *(const short8*)(g + (mf << 9));
    };

    // prologue: zero both buffers + dummy (halo cols/rows stay 0 forever)
    {
        unsigned int* xz = (unsigned int*)Xs;
        for (int i = tid; i < XsEL6 + 256; i += 256) xz[i] = 0u;
    }
    __syncthreads();
    dma_chunk(0, 0);
    __syncthreads();

    f32x4 acc[4][4];
    #pragma unroll
    for (int mf = 0; mf < 4; ++mf)
        #pragma unroll
        for (int nf = 0; nf < 4; ++nf)
            acc[mf][nf] = (f32x4){0.f, 0.f, 0.f, 0.f};

    short8 afc[4];
    loadA(0, 0, afc);

    for (int c = 0; c < 16; ++c) {
        const unsigned short* Xb = Xs + (c & 1) * XsEL6;
        #pragma unroll
        for (int t = 0; t < 9; ++t) {
            short8 afn[4];
            {
                int c2 = (t < 8) ? c : ((c + 1) & 15);
                int t2 = (t < 8) ? (t + 1) : 0;
                loadA(c2, t2, afn);
            }
            if (t == 2 && c < 15) dma_chunk(c + 1, (c + 1) & 1);
            const int kh = t / 3, kw = t % 3;
            short8 bfr[4];
            #pragma unroll
            for (int nf = 0; nf < 4; ++nf) {
                int cl = (nf << 4) + lane15 + kw;
                int gp = kg ^ ((cl >> 1) & 3);
                int el = ((wn + kh) * XCOLS + cl) * 32 + (gp << 3);
                bfr[nf] = *(const short8*)(Xb + el);
            }
            #pragma unroll
            for (int mf = 0; mf < 4; ++mf)
                #pragma unroll
                for (int nf = 0; nf < 4; ++nf)
                    acc[mf][nf] = __builtin_amdgcn_mfma_f32_16x16x32_bf16(
                        afc[mf], bfr[nf], acc[mf][nf], 0, 0, 0);
            #pragma unroll
            for (int mf = 0; mf < 4; ++mf) afc[mf] = afn[mf];
        }
        __syncthreads();             // buffer handoff (drains DMA + LDS)
    }

    // epilogue: demod, noise, bias, lrelu*sqrt(2)
    const float nstrength = nstr[0];
    float* outb = out + (size_t)(b * OC_ + oc0) * HW_ + (size_t)r0 * RES_;
    float nz[4];
    #pragma unroll
    for (int nf = 0; nf < 4; ++nf)
        nz[nf] = noise[(r0 + wn) * RES_ + (nf << 4) + lane15] * nstrength;
    #pragma unroll
    for (int mf = 0; mf < 4; ++mf) {
        #pragma unroll
        for (int r = 0; r < 4; ++r) {
            int ocl = (mf << 4) + (kg << 2) + r;
            float dc = dcoefs[b * OC_ + oc0 + ocl];
            float bv = bias[oc0 + ocl];
            #pragma unroll
            for (int nf = 0; nf < 4; ++nf) {
                int n = (wn << 6) + (nf << 4) + lane15;
                float vv = acc[mf][nf][r] * dc + nz[nf] + bv;
                vv = (vv >= 0.f ? vv : 0.2f * vv) * 1.4142135623730951f;
                outb[(size_t)ocl * HW_ + n] = vv;
            }
        }
    }
}

// ---------------- launch ---------------------------------------------------
extern "C" void kernel_launch(void* const* d_in, const int* in_sizes, int n_in,
                              void* d_out, int out_size, void* d_ws, size_t ws_size,
                              hipStream_t stream) {
    const float* x     = (const float*)d_in[0];
    const float* w     = (const float*)d_in[1];
    const float* cw    = (const float*)d_in[2];
    const float* aw    = (const float*)d_in[3];
    const float* ab    = (const float*)d_in[4];
    const float* bias  = (const float*)d_in[5];
    const float* noise = (const float*)d_in[6];
    const float* nstr  = (const float*)d_in[7];
    float* out = (float*)d_out;

    uint8_t* ws = (uint8_t*)d_ws;
    float* styles = (float*)ws;                              // 32 KB
    float* dcoefs = (float*)(ws + 32768);                    // 32 KB
    float* S2     = (float*)(ws + 65536);                    // 1 MB
    unsigned short* wbf   = (unsigned short*)(ws + 65536 + 1048576);  // 4.72 MB
    unsigned short* xpack = (unsigned short*)(ws + 8388608);          // 67.1 MB

    hipLaunchKernelGGL(k_styles, dim3(2048), dim3(256), 0, stream, w, aw, ab, styles);
    hipLaunchKernelGGL(k_xprep,  dim3(16384), dim3(256), 0, stream, x, styles, xpack);
    hipLaunchKernelGGL(k_wprep,  dim3(1024), dim3(256), 0, stream, cw, S2, wbf);
    hipLaunchKernelGGL(k_dcoef,  dim3(2048), dim3(256), 0, stream, styles, S2, dcoefs);
    hipLaunchKernelGGL(k_conv, dim3(2048), dim3(256), 0, stream,
                       xpack, dcoefs, wbf, bias, noise, nstr, out);
}